// Round 9
// baseline (282.003 us; speedup 1.0000x reference)
//
#include <hip/hip_runtime.h>

typedef __attribute__((ext_vector_type(8))) short short8;
typedef __attribute__((ext_vector_type(4))) float f32x4;

#define NHEADS 16
#define DK 64
#define SEQ 2048
#define DMODEL 1024

__device__ __forceinline__ unsigned short f2bf(float f) {
  union { float f; unsigned int u; } c; c.f = f;
  unsigned int u = c.u;
  return (unsigned short)((u + 0x7FFFu + ((u >> 16) & 1u)) >> 16);
}

__device__ __forceinline__ float exp2_hw(float x) {
  float y;
  asm("v_exp_f32 %0, %1" : "=v"(y) : "v"(x));
  return y;
}

__device__ __forceinline__ unsigned int cvtpk_bf16(float lo, float hi) {
  unsigned int r;
  asm("v_cvt_pk_bf16_f32 %0, %1, %2" : "=v"(r) : "v"(lo), "v"(hi));
  return r;
}

__device__ __forceinline__ short8 ldg16(const unsigned short* p) {
  return *reinterpret_cast<const short8*>(p);
}

__device__ __forceinline__ void gload_lds16(const unsigned short* g, unsigned short* l) {
  __builtin_amdgcn_global_load_lds(
      (const __attribute__((address_space(1))) unsigned int*)g,
      (__attribute__((address_space(3))) unsigned int*)l, 16, 0, 0);
}

struct ProjPtrs {
  const float* A0; const float* A1; const float* A2;
  const float* W0; const float* W1; const float* W2;
  const float* bias0; const float* bias1; const float* bias2;
  unsigned short* dst0; unsigned short* dst1; unsigned short* dst2;
};

// ---- projection GEMM with FUSED f32->bf16 cast: 128x128 tile, 4 waves, BK=32,
// double-buffered LDS, reg-staged (global f32 -> cvt_pk -> ds_write_b128).
// z=0: Q (pre-scaled 1/8*log2e, [B,H,S,64]); z=1: K; z=2: V transposed ([B,H,64,S])
__global__ __launch_bounds__(256) void gemm_proj(ProjPtrs p) {
  // staging: A bufs [2][4096] shorts @0, B bufs [2][4096] @8192 (32 KB);
  // V-transpose epilogue reuses [0..18431] (36 KB total).
  __shared__ __align__(16) unsigned short S[18432];
  const int mode = blockIdx.z;
  const float* A = mode == 0 ? p.A0 : (mode == 1 ? p.A1 : p.A2);
  const float* W = mode == 0 ? p.W0 : (mode == 1 ? p.W1 : p.W2);
  const float* bias = mode == 0 ? p.bias0 : (mode == 1 ? p.bias1 : p.bias2);
  unsigned short* dst = mode == 0 ? p.dst0 : (mode == 1 ? p.dst1 : p.dst2);
  const int m0 = blockIdx.y * 128, n0 = blockIdx.x * 128;
  const int t = threadIdx.x, lane = t & 63, w = t >> 6;
  const int wr = w >> 1, wc = w & 1;
  const int lr = lane >> 4, lc = lane & 15;
  const float* a_src0 = A + (size_t)(m0 + (t >> 2)) * DMODEL + (t & 3) * 8;
  const float* a_src1 = a_src0 + (size_t)64 * DMODEL;
  const float* w_src0 = W + (size_t)(n0 + (t >> 2)) * DMODEL + (t & 3) * 8;
  const float* w_src1 = w_src0 + (size_t)64 * DMODEL;

  f32x4 acc[4][4] = {};
  float4 ra0, ra1, ra2, ra3, rw0, rw1, rw2, rw3;

#define PLOADR(kk) do { \
    ra0 = *reinterpret_cast<const float4*>(a_src0 + (kk)); \
    ra1 = *reinterpret_cast<const float4*>(a_src0 + (kk) + 4); \
    ra2 = *reinterpret_cast<const float4*>(a_src1 + (kk)); \
    ra3 = *reinterpret_cast<const float4*>(a_src1 + (kk) + 4); \
    rw0 = *reinterpret_cast<const float4*>(w_src0 + (kk)); \
    rw1 = *reinterpret_cast<const float4*>(w_src0 + (kk) + 4); \
    rw2 = *reinterpret_cast<const float4*>(w_src1 + (kk)); \
    rw3 = *reinterpret_cast<const float4*>(w_src1 + (kk) + 4); } while (0)

#define PWRITER(bi) do { \
    uint4 u; \
    u.x = cvtpk_bf16(ra0.x, ra0.y); u.y = cvtpk_bf16(ra0.z, ra0.w); \
    u.z = cvtpk_bf16(ra1.x, ra1.y); u.w = cvtpk_bf16(ra1.z, ra1.w); \
    *reinterpret_cast<uint4*>(S + (bi) * 4096 + t * 8) = u; \
    u.x = cvtpk_bf16(ra2.x, ra2.y); u.y = cvtpk_bf16(ra2.z, ra2.w); \
    u.z = cvtpk_bf16(ra3.x, ra3.y); u.w = cvtpk_bf16(ra3.z, ra3.w); \
    *reinterpret_cast<uint4*>(S + (bi) * 4096 + 2048 + t * 8) = u; \
    u.x = cvtpk_bf16(rw0.x, rw0.y); u.y = cvtpk_bf16(rw0.z, rw0.w); \
    u.z = cvtpk_bf16(rw1.x, rw1.y); u.w = cvtpk_bf16(rw1.z, rw1.w); \
    *reinterpret_cast<uint4*>(S + 8192 + (bi) * 4096 + t * 8) = u; \
    u.x = cvtpk_bf16(rw2.x, rw2.y); u.y = cvtpk_bf16(rw2.z, rw2.w); \
    u.z = cvtpk_bf16(rw3.x, rw3.y); u.w = cvtpk_bf16(rw3.z, rw3.w); \
    *reinterpret_cast<uint4*>(S + 8192 + (bi) * 4096 + 2048 + t * 8) = u; } while (0)

  auto compute = [&](const int bi) {
    const unsigned short* Ab = S + bi * 4096;
    const unsigned short* Bb = S + 8192 + bi * 4096;
    short8 a[4], b[4];
#pragma unroll
    for (int i = 0; i < 4; ++i) {
      a[i] = *reinterpret_cast<const short8*>(Ab + (wr * 64 + i * 16 + lc) * 32 + lr * 8);
      b[i] = *reinterpret_cast<const short8*>(Bb + (wc * 64 + i * 16 + lc) * 32 + lr * 8);
    }
#pragma unroll
    for (int mi = 0; mi < 4; ++mi)
#pragma unroll
      for (int ni = 0; ni < 4; ++ni)
        acc[mi][ni] = __builtin_amdgcn_mfma_f32_16x16x32_bf16(a[mi], b[ni], acc[mi][ni], 0, 0, 0);
  };

  PLOADR(0);
  PWRITER(0);
  __syncthreads();
  int buf = 0;
  for (int k0 = 0; k0 < DMODEL; k0 += 32) {
    if (k0 < DMODEL - 32) PLOADR(k0 + 32);
    __builtin_amdgcn_sched_barrier(0);
    compute(buf);
    __syncthreads();
    if (k0 < DMODEL - 32) PWRITER(buf ^ 1);
    __syncthreads();
    buf ^= 1;
  }

  if (mode == 2) {
    // V: transpose 64x64 wave tile through LDS -> contiguous 128B row-segment stores
    unsigned short* T = S + w * 4608;  // 64 rows x stride 72
    const int h = (n0 + wc * 64) >> 6;
    const int rb0 = m0 + wr * 64;
    const int bb = rb0 >> 11, s_base = rb0 & 2047;
#pragma unroll
    for (int mi = 0; mi < 4; ++mi) {
#pragma unroll
      for (int ni = 0; ni < 4; ++ni) {
        const float bv = bias[n0 + wc * 64 + ni * 16 + lc];
        uint2 pk;
        pk.x = cvtpk_bf16(acc[mi][ni][0] + bv, acc[mi][ni][1] + bv);
        pk.y = cvtpk_bf16(acc[mi][ni][2] + bv, acc[mi][ni][3] + bv);
        *reinterpret_cast<uint2*>(&T[(ni * 16 + lc) * 72 + mi * 16 + lr * 4]) = pk;
      }
    }
    __builtin_amdgcn_sched_barrier(0);
    unsigned short* dstb = dst + ((size_t)(bb * NHEADS + h) * 64) * 2048 + s_base;
#pragma unroll
    for (int i = 0; i < 8; ++i) {
      const int drow = i * 8 + (lane >> 3), scol = (lane & 7) * 8;
      const short8 val = *reinterpret_cast<const short8*>(&T[drow * 72 + scol]);
      *reinterpret_cast<short8*>(dstb + (size_t)drow * 2048 + scol) = val;
    }
  } else {
    const float sc = (mode == 0) ? 0.18033688f : 1.0f;  // 1/8 * log2(e) for exp2-domain softmax
#pragma unroll
    for (int mi = 0; mi < 4; ++mi) {
#pragma unroll
      for (int ni = 0; ni < 4; ++ni) {
        const int cg = n0 + wc * 64 + ni * 16 + lc;
        const int rb = m0 + wr * 64 + mi * 16 + lr * 4;
        const float bv = bias[cg];
        const int h = cg >> 6, d = cg & 63;
#pragma unroll
        for (int j = 0; j < 4; ++j) {
          const int rg = rb + j;
          const int bb = rg >> 11, s = rg & 2047;
          dst[((size_t)(bb * NHEADS + h) * SEQ + s) * DK + d] = f2bf((acc[mi][ni][j] + bv) * sc);
        }
      }
    }
  }
}

// ---- output GEMM: 128x64 tile, 4 waves (64x32 each), BK=32, dbuf;
// A (Oh bf16) via global_load_lds, B (w_o f32) reg-staged with fused cast.
__global__ __launch_bounds__(256) void gemm_out(const unsigned short* __restrict__ A,
                                                const float* __restrict__ W,
                                                const float* __restrict__ bias,
                                                float* __restrict__ out) {
  __shared__ __align__(16) unsigned short S[12288];  // A bufs [2][4096] @0, B bufs [2][2048] @8192
  const int m0 = blockIdx.y * 128, n0 = blockIdx.x * 64;
  const int t = threadIdx.x, lane = t & 63, w = t >> 6;
  const int wr = w >> 1, wc = w & 1;
  const int lr = lane >> 4, lc = lane & 15;
  const unsigned short* a_src0 = A + (size_t)(m0 + (t >> 2)) * DMODEL + (t & 3) * 8;
  const unsigned short* a_src1 = a_src0 + (size_t)64 * DMODEL;
  const float* w_src0 = W + (size_t)(n0 + (t >> 2)) * DMODEL + (t & 3) * 8;

  f32x4 acc[4][2] = {};
  float4 rw0, rw1;

#define OSTAGE_A(kk, bi) do { \
    gload_lds16(a_src0 + (kk), S + (bi) * 4096 + t * 8); \
    gload_lds16(a_src1 + (kk), S + (bi) * 4096 + 2048 + t * 8); } while (0)

#define OLOADR(kk) do { \
    rw0 = *reinterpret_cast<const float4*>(w_src0 + (kk)); \
    rw1 = *reinterpret_cast<const float4*>(w_src0 + (kk) + 4); } while (0)

#define OWRITER(bi) do { \
    uint4 u; \
    u.x = cvtpk_bf16(rw0.x, rw0.y); u.y = cvtpk_bf16(rw0.z, rw0.w); \
    u.z = cvtpk_bf16(rw1.x, rw1.y); u.w = cvtpk_bf16(rw1.z, rw1.w); \
    *reinterpret_cast<uint4*>(S + 8192 + (bi) * 2048 + t * 8) = u; } while (0)

  auto compute = [&](const int bi) {
    const unsigned short* Ab = S + bi * 4096;
    const unsigned short* Bb = S + 8192 + bi * 2048;
    short8 a[4], b[2];
#pragma unroll
    for (int i = 0; i < 4; ++i)
      a[i] = *reinterpret_cast<const short8*>(Ab + (wr * 64 + i * 16 + lc) * 32 + lr * 8);
#pragma unroll
    for (int i = 0; i < 2; ++i)
      b[i] = *reinterpret_cast<const short8*>(Bb + (wc * 32 + i * 16 + lc) * 32 + lr * 8);
#pragma unroll
    for (int mi = 0; mi < 4; ++mi)
#pragma unroll
      for (int ni = 0; ni < 2; ++ni)
        acc[mi][ni] = __builtin_amdgcn_mfma_f32_16x16x32_bf16(a[mi], b[ni], acc[mi][ni], 0, 0, 0);
  };

  OSTAGE_A(0, 0);
  OLOADR(0);
  OWRITER(0);
  __syncthreads();
  int buf = 0;
  for (int k0 = 0; k0 < DMODEL; k0 += 32) {
    if (k0 < DMODEL - 32) {
      OSTAGE_A(k0 + 32, buf ^ 1);
      OLOADR(k0 + 32);
    }
    __builtin_amdgcn_sched_barrier(0);
    compute(buf);
    __syncthreads();
    if (k0 < DMODEL - 32) OWRITER(buf ^ 1);
    __syncthreads();
    buf ^= 1;
  }

#pragma unroll
  for (int mi = 0; mi < 4; ++mi)
#pragma unroll
    for (int ni = 0; ni < 2; ++ni) {
      const int cg = n0 + wc * 32 + ni * 16 + lc;
      const int rb = m0 + wr * 64 + mi * 16 + lr * 4;
      const float bv = bias[cg];
#pragma unroll
      for (int j = 0; j < 4; ++j)
        out[(size_t)(rb + j) * DMODEL + cg] = acc[mi][ni][j] + bv;
    }
}

// Flash attention: unchanged (82 µs anchor).
__global__ __launch_bounds__(256) void attn_fwd(const unsigned short* __restrict__ Qh,
                                                const unsigned short* __restrict__ Kh,
                                                const unsigned short* __restrict__ Vt,
                                                unsigned short* __restrict__ Oh) {
  __shared__ __align__(16) unsigned short Ktile[2][4096];   // [kv 64][d 64], swizzled
  __shared__ __align__(16) unsigned short Vtile[2][4096];   // [d 64][kv 64], swizzled
  __shared__ __align__(16) unsigned short P[4][32][76];     // per-wave [q][kv], padded
  const int t = threadIdx.x, w = t >> 6, lane = t & 63;
  const int bx = ((blockIdx.x & 7) << 6) | (blockIdx.x >> 3);
  const int bh = bx >> 4, qblk = bx & 15;
  const int q0 = qblk * 128 + w * 32;
  const unsigned short* Qp = Qh + (size_t)bh * SEQ * DK;
  const unsigned short* Kp = Kh + (size_t)bh * SEQ * DK;
  const unsigned short* Vp = Vt + (size_t)bh * DK * SEQ;
  const int r = lane & 15, g = lane >> 4;

  const short8 qa0 = ldg16(Qp + (size_t)(q0 + r) * DK + g * 8);
  const short8 qa1 = ldg16(Qp + (size_t)(q0 + r) * DK + 32 + g * 8);
  const short8 qb0 = ldg16(Qp + (size_t)(q0 + 16 + r) * DK + g * 8);
  const short8 qb1 = ldg16(Qp + (size_t)(q0 + 16 + r) * DK + 32 + g * 8);

  const int c0 = w * 64 + lane, c1 = c0 + 256;
  const int r0 = c0 >> 3, s0 = (c0 & 7) ^ (r0 & 7);
  const int r1 = c1 >> 3, s1 = (c1 & 7) ^ (r1 & 7);
  const unsigned short* ks0 = Kp + r0 * DK + s0 * 8;
  const unsigned short* ks1 = Kp + r1 * DK + s1 * 8;
  const unsigned short* vs0 = Vp + (size_t)r0 * SEQ + s0 * 8;
  const unsigned short* vs1 = Vp + (size_t)r1 * SEQ + s1 * 8;

  float mA = -1e30f, lA = 0.f, mB = -1e30f, lB = 0.f;
  f32x4 oA[4] = {}, oB[4] = {};

  const int sw0 = ((g ^ (r & 7)) << 3);
  const int sw1 = (((g + 4) ^ (r & 7)) << 3);
  char* prowA = (char*)&P[w][r][0];
  char* prowB = (char*)&P[w][16 + r][0];

  gload_lds16(ks0, &Ktile[0][w * 512]);
  gload_lds16(ks1, &Ktile[0][2048 + w * 512]);
  gload_lds16(vs0, &Vtile[0][w * 512]);
  gload_lds16(vs1, &Vtile[0][2048 + w * 512]);
  __syncthreads();

  int buf = 0;
  for (int kt = 0; kt < 32; ++kt) {
    if (kt < 31) {
      const int kvn = (kt + 1) * 64;
      gload_lds16(ks0 + kvn * DK, &Ktile[buf ^ 1][w * 512]);
      gload_lds16(ks1 + kvn * DK, &Ktile[buf ^ 1][2048 + w * 512]);
      gload_lds16(vs0 + kvn, &Vtile[buf ^ 1][w * 512]);
      gload_lds16(vs1 + kvn, &Vtile[buf ^ 1][2048 + w * 512]);
    }
    f32x4 sA[4] = {}, sB[4] = {};
    __builtin_amdgcn_s_setprio(1);
#pragma unroll
    for (int nt = 0; nt < 4; ++nt) {
      const short8 k0 = *reinterpret_cast<const short8*>(&Ktile[buf][(nt * 16 + r) * 64 + sw0]);
      const short8 k1 = *reinterpret_cast<const short8*>(&Ktile[buf][(nt * 16 + r) * 64 + sw1]);
      sA[nt] = __builtin_amdgcn_mfma_f32_16x16x32_bf16(k0, qa0, sA[nt], 0, 0, 0);
      sA[nt] = __builtin_amdgcn_mfma_f32_16x16x32_bf16(k1, qa1, sA[nt], 0, 0, 0);
      sB[nt] = __builtin_amdgcn_mfma_f32_16x16x32_bf16(k0, qb0, sB[nt], 0, 0, 0);
      sB[nt] = __builtin_amdgcn_mfma_f32_16x16x32_bf16(k1, qb1, sB[nt], 0, 0, 0);
    }
    __builtin_amdgcn_s_setprio(0);
    {
      f32x4 pm;
#pragma unroll
      for (int j = 0; j < 4; ++j)
        pm[j] = fmaxf(fmaxf(sA[0][j], sA[1][j]), fmaxf(sA[2][j], sA[3][j]));
      float pmax = fmaxf(fmaxf(pm[0], pm[1]), fmaxf(pm[2], pm[3]));
      pmax = fmaxf(pmax, __shfl_xor(pmax, 16));
      pmax = fmaxf(pmax, __shfl_xor(pmax, 32));
      if (!__all(pmax - mA <= 8.f)) {
        const float mn = fmaxf(mA, pmax);
        const float al = exp2_hw(mA - mn);
        mA = mn; lA *= al;
        float alj[4];
#pragma unroll
        for (int j = 0; j < 4; ++j) alj[j] = __shfl(al, 4 * g + j, 16);
#pragma unroll
        for (int nt = 0; nt < 4; ++nt)
#pragma unroll
          for (int j = 0; j < 4; ++j) oA[nt][j] *= alj[j];
      }
#pragma unroll
      for (int nt = 0; nt < 4; ++nt)
#pragma unroll
        for (int j = 0; j < 4; ++j) sA[nt][j] = exp2_hw(sA[nt][j] - mA);
      f32x4 s4;
#pragma unroll
      for (int j = 0; j < 4; ++j) s4[j] = (sA[0][j] + sA[1][j]) + (sA[2][j] + sA[3][j]);
      float sum = (s4[0] + s4[1]) + (s4[2] + s4[3]);
      sum += __shfl_xor(sum, 16);
      sum += __shfl_xor(sum, 32);
      lA += sum;
#pragma unroll
      for (int nt = 0; nt < 4; ++nt) {
        uint2 pk;
        pk.x = cvtpk_bf16(sA[nt][0], sA[nt][1]);
        pk.y = cvtpk_bf16(sA[nt][2], sA[nt][3]);
        *reinterpret_cast<uint2*>(prowA + nt * 32 + g * 8) = pk;
      }
    }
    {
      f32x4 pm;
#pragma unroll
      for (int j = 0; j < 4; ++j)
        pm[j] = fmaxf(fmaxf(sB[0][j], sB[1][j]), fmaxf(sB[2][j], sB[3][j]));
      float pmax = fmaxf(fmaxf(pm[0], pm[1]), fmaxf(pm[2], pm[3]));
      pmax = fmaxf(pmax, __shfl_xor(pmax, 16));
      pmax = fmaxf(pmax, __shfl_xor(pmax, 32));
      if (!__all(pmax - mB <= 8.f)) {
        const float mn = fmaxf(mB, pmax);
        const float al = exp2_hw(mB - mn);
        mB = mn; lB *= al;
        float alj[4];
#pragma unroll
        for (int j = 0; j < 4; ++j) alj[j] = __shfl(al, 4 * g + j, 16);
#pragma unroll
        for (int nt = 0; nt < 4; ++nt)
#pragma unroll
          for (int j = 0; j < 4; ++j) oB[nt][j] *= alj[j];
      }
#pragma unroll
      for (int nt = 0; nt < 4; ++nt)
#pragma unroll
        for (int j = 0; j < 4; ++j) sB[nt][j] = exp2_hw(sB[nt][j] - mB);
      f32x4 s4;
#pragma unroll
      for (int j = 0; j < 4; ++j) s4[j] = (sB[0][j] + sB[1][j]) + (sB[2][j] + sB[3][j]);
      float sum = (s4[0] + s4[1]) + (s4[2] + s4[3]);
      sum += __shfl_xor(sum, 16);
      sum += __shfl_xor(sum, 32);
      lB += sum;
#pragma unroll
      for (int nt = 0; nt < 4; ++nt) {
        uint2 pk;
        pk.x = cvtpk_bf16(sB[nt][0], sB[nt][1]);
        pk.y = cvtpk_bf16(sB[nt][2], sB[nt][3]);
        *reinterpret_cast<uint2*>(prowB + nt * 32 + g * 8) = pk;
      }
    }
    union { short8 v; unsigned long long q[2]; } pA0, pA1, pB0, pB1;
    pA0.q[0] = *reinterpret_cast<const unsigned long long*>(prowA + g * 16);
    pA0.q[1] = *reinterpret_cast<const unsigned long long*>(prowA + g * 16 + 8);
    pA1.q[0] = *reinterpret_cast<const unsigned long long*>(prowA + 64 + g * 16);
    pA1.q[1] = *reinterpret_cast<const unsigned long long*>(prowA + 64 + g * 16 + 8);
    pB0.q[0] = *reinterpret_cast<const unsigned long long*>(prowB + g * 16);
    pB0.q[1] = *reinterpret_cast<const unsigned long long*>(prowB + g * 16 + 8);
    pB1.q[0] = *reinterpret_cast<const unsigned long long*>(prowB + 64 + g * 16);
    pB1.q[1] = *reinterpret_cast<const unsigned long long*>(prowB + 64 + g * 16 + 8);
    __builtin_amdgcn_s_setprio(1);
#pragma unroll
    for (int nt = 0; nt < 4; ++nt) {
      const short8 v0 = *reinterpret_cast<const short8*>(&Vtile[buf][(nt * 16 + r) * 64 + sw0]);
      const short8 v1 = *reinterpret_cast<const short8*>(&Vtile[buf][(nt * 16 + r) * 64 + sw1]);
      oA[nt] = __builtin_amdgcn_mfma_f32_16x16x32_bf16(pA0.v, v0, oA[nt], 0, 0, 0);
      oA[nt] = __builtin_amdgcn_mfma_f32_16x16x32_bf16(pA1.v, v1, oA[nt], 0, 0, 0);
      oB[nt] = __builtin_amdgcn_mfma_f32_16x16x32_bf16(pB0.v, v0, oB[nt], 0, 0, 0);
      oB[nt] = __builtin_amdgcn_mfma_f32_16x16x32_bf16(pB1.v, v1, oB[nt], 0, 0, 0);
    }
    __builtin_amdgcn_s_setprio(0);
    __syncthreads();
    buf ^= 1;
  }

  const float invA = 1.f / lA, invB = 1.f / lB;
  float ivA[4], ivB[4];
#pragma unroll
  for (int j = 0; j < 4; ++j) {
    ivA[j] = __shfl(invA, 4 * g + j, 16);
    ivB[j] = __shfl(invB, 4 * g + j, 16);
  }
  const size_t ob = ((size_t)((bh >> 4) * SEQ + q0)) * DMODEL + (size_t)(bh & 15) * DK;
#pragma unroll
  for (int nt = 0; nt < 4; ++nt)
#pragma unroll
    for (int j = 0; j < 4; ++j) {
      Oh[ob + (size_t)(g * 4 + j) * DMODEL + nt * 16 + r] = f2bf(oA[nt][j] * ivA[j]);
      Oh[ob + (size_t)(16 + g * 4 + j) * DMODEL + nt * 16 + r] = f2bf(oB[nt][j] * ivB[j]);
    }
}

extern "C" void kernel_launch(void* const* d_in, const int* in_sizes, int n_in,
                              void* d_out, int out_size, void* d_ws, size_t ws_size,
                              hipStream_t stream) {
  const float* q   = (const float*)d_in[0];
  const float* k   = (const float*)d_in[1];
  const float* v   = (const float*)d_in[2];
  const float* w_q = (const float*)d_in[3];
  const float* b_q = (const float*)d_in[4];
  const float* w_k = (const float*)d_in[5];
  const float* b_k = (const float*)d_in[6];
  const float* w_v = (const float*)d_in[7];
  const float* b_v = (const float*)d_in[8];
  const float* w_o = (const float*)d_in[9];
  const float* b_o = (const float*)d_in[10];
  float* out = (float*)d_out;
  char* ws = (char*)d_ws;
  const size_t MB = (size_t)1 << 20;
  unsigned short* Qh  = (unsigned short*)(ws + 32 * MB);
  unsigned short* Kh  = (unsigned short*)(ws + 40 * MB);
  unsigned short* Vt  = (unsigned short*)(ws + 48 * MB);
  unsigned short* Oh  = (unsigned short*)(ws + 56 * MB);

  ProjPtrs p;
  p.A0 = q; p.A1 = k; p.A2 = v;
  p.W0 = w_q; p.W1 = w_k; p.W2 = w_v;
  p.bias0 = b_q; p.bias1 = b_k; p.bias2 = b_v;
  p.dst0 = Qh; p.dst1 = Kh; p.dst2 = Vt;
  gemm_proj<<<dim3(8, 32, 3), 256, 0, stream>>>(p);

  attn_fwd<<<512, 256, 0, stream>>>(Qh, Kh, Vt, Oh);

  gemm_out<<<dim3(16, 32), 256, 0, stream>>>(Oh, w_o, b_o, out);
}